// Round 1
// baseline (465.111 us; speedup 1.0000x reference)
//
#include <hip/hip_runtime.h>
#include <math.h>

#define BB      16
#define SECL    16
#define WORDL   256
#define SRCLEN  4096     // SECL*WORDL
#define DIM     1024
#define FSZ     2
#define GL      (FSZ*WORDL)   // 512 gathered positions per batch

// ---------------------------------------------------------------------------
// K1: dec_feature[b][i] = b_dec[i] + dot(dec_hidden[b,:], W_dec[i,:])
//     plus (blockIdx.x==16) top-2 of focus per batch (tie -> lowest idx,
//     matching jax.lax.top_k).
// grid (17,16) x 256 threads. GEMM tile: 64 i-values per block, 4 threads/i.
// ---------------------------------------------------------------------------
__global__ __launch_bounds__(256) void k_decproj_topk(
    const float* __restrict__ dec_hidden, const float* __restrict__ W_dec,
    const float* __restrict__ b_dec, const float* __restrict__ focus,
    float* __restrict__ dec_feature, int* __restrict__ top_idx,
    float* __restrict__ top_val)
{
    if (blockIdx.x == 16) {
        if (threadIdx.x == 0) {
            int b = blockIdx.y;
            const float* f = focus + b * SECL;
            int i0 = 0; float v0 = f[0];
            for (int s = 1; s < SECL; s++) if (f[s] > v0) { v0 = f[s]; i0 = s; }
            int i1 = -1; float v1 = -INFINITY;
            for (int s = 0; s < SECL; s++)
                if (s != i0 && f[s] > v1) { v1 = f[s]; i1 = s; }
            top_idx[b*2+0] = i0; top_idx[b*2+1] = i1;
            top_val[b*2+0] = v0; top_val[b*2+1] = v1;
        }
        return;
    }
    int b = blockIdx.y;
    int t = threadIdx.x;
    int i = blockIdx.x * 64 + (t >> 2);   // output column
    int c = t & 3;                        // k-chunk (256 floats each)
    const float4* Wr = (const float4*)(W_dec + (size_t)i * DIM + c * 256);
    const float4* Dr = (const float4*)(dec_hidden + (size_t)b * DIM + c * 256);
    float acc = 0.f;
    #pragma unroll 8
    for (int j = 0; j < 64; j++) {
        float4 w = Wr[j], d = Dr[j];
        acc += w.x*d.x + w.y*d.y + w.z*d.z + w.w*d.w;
    }
    // sum the 4 chunk partials (lanes 4m..4m+3 are contiguous within a wave)
    acc += __shfl_down(acc, 2);
    acc += __shfl_down(acc, 1);
    if (c == 0) dec_feature[(size_t)b * DIM + i] = acc + b_dec[i];
}

// ---------------------------------------------------------------------------
// K2: gathered scores (one wave per gathered position, 8192 waves) +
//     full coverage -> coverage_out copy (64 extra blocks).
// ---------------------------------------------------------------------------
__global__ __launch_bounds__(256) void k_score_cov(
    const float* __restrict__ enc_feature, const float* __restrict__ coverage,
    const float* __restrict__ dec_feature, const float* __restrict__ v,
    const float* __restrict__ w_cov, const int* __restrict__ top_idx,
    float* __restrict__ score_g, float* __restrict__ cov_out)
{
    int bid = blockIdx.x;
    if (bid >= 2048) {
        int idx = (bid - 2048) * 256 + threadIdx.x;   // float4 index, 16384 total
        ((float4*)cov_out)[idx] = ((const float4*)coverage)[idx];
        return;
    }
    int w    = bid * 4 + (threadIdx.x >> 6);   // wave id in [0, 8192)
    int lane = threadIdx.x & 63;
    int b  = w >> 9;           // 512 waves per batch
    int r  = w & 511;          // gathered index
    int k  = r >> 8;           // which of the 2 sections
    int wp = r & 255;          // word within section
    int sec = top_idx[b*2 + k];
    int s   = sec * WORDL + wp;
    float cv = coverage[(size_t)b * SRCLEN + s];
    const float4* ef = (const float4*)(enc_feature + ((size_t)b * SRCLEN + s) * DIM);
    const float4* df = (const float4*)(dec_feature + (size_t)b * DIM);
    const float4* vv = (const float4*)v;
    const float4* wc = (const float4*)w_cov;
    float acc = 0.f;
    #pragma unroll
    for (int q = 0; q < 4; q++) {
        int e4 = q * 64 + lane;                  // coalesced: 64 lanes x 16B
        float4 a = ef[e4], d = df[e4], wcv = wc[e4], vt = vv[e4];
        acc += tanhf(a.x + d.x + cv * wcv.x) * vt.x;
        acc += tanhf(a.y + d.y + cv * wcv.y) * vt.y;
        acc += tanhf(a.z + d.z + cv * wcv.z) * vt.z;
        acc += tanhf(a.w + d.w + cv * wcv.w) * vt.w;
    }
    #pragma unroll
    for (int off = 32; off; off >>= 1) acc += __shfl_down(acc, off);
    if (lane == 0) score_g[b * GL + r] = acc;
}

// ---------------------------------------------------------------------------
// K3: per-batch masked softmax over 512 gathered scores + focus scaling +
//     global renorm + scatter into attn_dist / coverage_out.
// Algebra: p_norm = e*mask/sum(e*mask);  T = sum_k f_k*sum_w p_norm;
//          attn   = f_k*p_norm/T = f_k*e*mask / sum(f_k*e*mask)   (Sm cancels)
// grid 16 x 256 threads, 2 elements/thread.
// ---------------------------------------------------------------------------
__device__ __forceinline__ float block_reduce(float val, int is_max) {
    __shared__ float red[4];
    int lane = threadIdx.x & 63, wid = threadIdx.x >> 6;
    #pragma unroll
    for (int off = 32; off; off >>= 1) {
        float o = __shfl_down(val, off);
        val = is_max ? fmaxf(val, o) : val + o;
    }
    if (lane == 0) red[wid] = val;
    __syncthreads();
    if (threadIdx.x == 0) {
        float r = red[0];
        for (int i = 1; i < 4; i++) r = is_max ? fmaxf(r, red[i]) : r + red[i];
        red[0] = r;
    }
    __syncthreads();
    float result = red[0];
    __syncthreads();   // protect red[] before next call
    return result;
}

__global__ __launch_bounds__(256) void k_softmax_scatter(
    const float* __restrict__ enc_mask, const float* __restrict__ coverage,
    const int* __restrict__ top_idx, const float* __restrict__ top_val,
    const float* __restrict__ score_g,
    float* __restrict__ attn_g, float* __restrict__ attn_out,
    float* __restrict__ cov_out)
{
    int b = blockIdx.x;
    int t = threadIdx.x;
    float sc[2], mk[2], fv[2];
    int ss[2];
    #pragma unroll
    for (int u = 0; u < 2; u++) {
        int r  = t + u * 256;
        int k  = r >> 8, wp = r & 255;
        int sec = top_idx[b*2 + k];
        int s   = sec * WORDL + wp;
        ss[u] = s;
        sc[u] = score_g[b * GL + r];
        mk[u] = enc_mask[(size_t)b * SRCLEN + s];
        fv[u] = top_val[b*2 + k];
    }
    float m  = block_reduce(fmaxf(sc[0], sc[1]), 1);
    float e0 = expf(sc[0] - m), e1 = expf(sc[1] - m);
    float Tn = block_reduce(fv[0]*e0*mk[0] + fv[1]*e1*mk[1], 0);
    float inv = 1.0f / Tn;
    #pragma unroll
    for (int u = 0; u < 2; u++) {
        int r = t + u * 256;
        float a = fv[u] * (u ? e1 : e0) * mk[u] * inv;
        attn_g[b * GL + r] = a;
        attn_out[(size_t)b * SRCLEN + ss[u]] = a;
        cov_out [(size_t)b * SRCLEN + ss[u]] = coverage[(size_t)b * SRCLEN + ss[u]] + a;
    }
}

// ---------------------------------------------------------------------------
// K4: context[b][:] = sum over 512 gathered rows of attn * enc_output[row][:]
// grid (16 splits, 16 batches) x 256 threads; each block sums 32 rows,
// float4-coalesced (256 threads x 16B = full 4KB row), atomicAdd partials.
// ---------------------------------------------------------------------------
__global__ __launch_bounds__(256) void k_context(
    const float* __restrict__ enc_output, const int* __restrict__ top_idx,
    const float* __restrict__ attn_g, float* __restrict__ context)
{
    int b  = blockIdx.y;
    int sp = blockIdx.x;        // 0..15
    int t  = threadIdx.x;       // float4 index over DIM/4 = 256
    int i0 = top_idx[b*2], i1 = top_idx[b*2 + 1];
    float4 acc = {0.f, 0.f, 0.f, 0.f};
    #pragma unroll 4
    for (int j = 0; j < 32; j++) {
        int r  = sp * 32 + j;
        int k  = r >> 8, wp = r & 255;
        int s  = (k ? i1 : i0) * WORDL + wp;
        float a = attn_g[b * GL + r];
        float4 e = ((const float4*)(enc_output + ((size_t)b * SRCLEN + s) * DIM))[t];
        acc.x += a * e.x; acc.y += a * e.y; acc.z += a * e.z; acc.w += a * e.w;
    }
    float* ctx = context + (size_t)b * DIM + t * 4;
    atomicAdd(ctx + 0, acc.x);
    atomicAdd(ctx + 1, acc.y);
    atomicAdd(ctx + 2, acc.z);
    atomicAdd(ctx + 3, acc.w);
}

// ---------------------------------------------------------------------------
extern "C" void kernel_launch(void* const* d_in, const int* in_sizes, int n_in,
                              void* d_out, int out_size, void* d_ws, size_t ws_size,
                              hipStream_t stream) {
    const float* dec_hidden  = (const float*)d_in[0];   // [16,1024]
    const float* enc_output  = (const float*)d_in[1];   // [16,4096,1024]
    const float* enc_feature = (const float*)d_in[2];   // [16,4096,1024]
    const float* enc_mask    = (const float*)d_in[3];   // [16,4096]
    // d_in[4] = sec_attn : unused by the reference
    const float* coverage    = (const float*)d_in[5];   // [16,4096]
    const float* focus       = (const float*)d_in[6];   // [16,16]
    const float* W_dec       = (const float*)d_in[7];   // [1024,1024]
    const float* b_dec       = (const float*)d_in[8];   // [1024]
    const float* v           = (const float*)d_in[9];   // [1024]
    const float* w_cov       = (const float*)d_in[10];  // [1024]

    float* out      = (float*)d_out;
    float* context  = out;                        // 16*1024  = 16384
    float* attn_out = out + 16384;                // 16*4096  = 65536
    float* cov_out  = out + 16384 + 65536;        // 16*4096  = 65536

    float* ws          = (float*)d_ws;
    float* dec_feature = ws;                      // 16384 floats
    int*   top_idx     = (int*)(ws + 16384);      // 32 ints
    float* top_val     = ws + 16384 + 32;         // 32 floats
    float* score_g     = ws + 16448;              // 16*512 = 8192
    float* attn_g      = ws + 24640;              // 16*512 = 8192

    // attn_dist needs zeros (scatter of 512/4096 per batch);
    // context needs zeros (atomicAdd accumulation). cov_out fully overwritten.
    hipMemsetAsync(d_out, 0, (size_t)out_size * sizeof(float), stream);

    k_decproj_topk<<<dim3(17, 16), 256, 0, stream>>>(
        dec_hidden, W_dec, b_dec, focus, dec_feature, top_idx, top_val);

    k_score_cov<<<dim3(2112), 256, 0, stream>>>(
        enc_feature, coverage, dec_feature, v, w_cov, top_idx, score_g, cov_out);

    k_softmax_scatter<<<dim3(16), 256, 0, stream>>>(
        enc_mask, coverage, top_idx, top_val, score_g, attn_g, attn_out, cov_out);

    k_context<<<dim3(16, 16), 256, 0, stream>>>(
        enc_output, top_idx, attn_g, context);
}

// Round 2
// 461.877 us; speedup vs baseline: 1.0070x; 1.0070x over previous
//
#include <hip/hip_runtime.h>
#include <math.h>

#define BB      16
#define SECL    16
#define WORDL   256
#define SRCLEN  4096     // SECL*WORDL
#define DIM     1024
#define FSZ     2
#define GL      (FSZ*WORDL)   // 512 gathered positions per batch

// fast tanh: 1 - 2/(e^{2x}+1), with clamp so e^{2x} never overflows.
// |err| ~1e-6 rel (v_exp_f32 + v_rcp_f32 approx), fine vs 2e-2 threshold.
__device__ __forceinline__ float fast_tanh(float x) {
    x = fminf(fmaxf(x, -10.f), 10.f);
    float e = __expf(2.f * x);
    return 1.f - 2.f * __builtin_amdgcn_rcpf(e + 1.f);
}

// ---------------------------------------------------------------------------
// K1: dec_feature[b][i] = b_dec[i] + dot(dec_hidden[b,:], W_dec[i,:])
//     blockIdx.x==16: top-2 of focus per batch (tie -> lowest idx, matching
//     jax.lax.top_k) + zero context[b] (so K4 can atomicAdd, no memset).
// grid (17,16) x 256 threads. GEMM tile: 64 i-values per block, 4 threads/i.
// ---------------------------------------------------------------------------
__global__ __launch_bounds__(256) void k_decproj_topk(
    const float* __restrict__ dec_hidden, const float* __restrict__ W_dec,
    const float* __restrict__ b_dec, const float* __restrict__ focus,
    float* __restrict__ dec_feature, int* __restrict__ top_idx,
    float* __restrict__ top_val, float* __restrict__ context)
{
    if (blockIdx.x == 16) {
        int b = blockIdx.y;
        // zero context row for this batch: 1024 floats = 256 x float4
        float4 z = {0.f, 0.f, 0.f, 0.f};
        ((float4*)(context + (size_t)b * DIM))[threadIdx.x] = z;
        if (threadIdx.x == 0) {
            const float* f = focus + b * SECL;
            int i0 = 0; float v0 = f[0];
            for (int s = 1; s < SECL; s++) if (f[s] > v0) { v0 = f[s]; i0 = s; }
            int i1 = -1; float v1 = -INFINITY;
            for (int s = 0; s < SECL; s++)
                if (s != i0 && f[s] > v1) { v1 = f[s]; i1 = s; }
            top_idx[b*2+0] = i0; top_idx[b*2+1] = i1;
            top_val[b*2+0] = v0; top_val[b*2+1] = v1;
        }
        return;
    }
    int b = blockIdx.y;
    int t = threadIdx.x;
    int i = blockIdx.x * 64 + (t >> 2);   // output column
    int c = t & 3;                        // k-chunk (256 floats each)
    const float4* Wr = (const float4*)(W_dec + (size_t)i * DIM + c * 256);
    const float4* Dr = (const float4*)(dec_hidden + (size_t)b * DIM + c * 256);
    float acc = 0.f;
    #pragma unroll 8
    for (int j = 0; j < 64; j++) {
        float4 w = Wr[j], d = Dr[j];
        acc += w.x*d.x + w.y*d.y + w.z*d.z + w.w*d.w;
    }
    acc += __shfl_down(acc, 2);
    acc += __shfl_down(acc, 1);
    if (c == 0) dec_feature[(size_t)b * DIM + i] = acc + b_dec[i];
}

// ---------------------------------------------------------------------------
// K2: gathered scores (one wave per gathered position, 8192 waves) +
//     full coverage -> coverage_out copy (64 extra blocks).
// ---------------------------------------------------------------------------
__global__ __launch_bounds__(256) void k_score_cov(
    const float* __restrict__ enc_feature, const float* __restrict__ coverage,
    const float* __restrict__ dec_feature, const float* __restrict__ v,
    const float* __restrict__ w_cov, const int* __restrict__ top_idx,
    float* __restrict__ score_g, float* __restrict__ cov_out)
{
    int bid = blockIdx.x;
    if (bid >= 2048) {
        int idx = (bid - 2048) * 256 + threadIdx.x;   // float4 index, 16384 total
        ((float4*)cov_out)[idx] = ((const float4*)coverage)[idx];
        return;
    }
    int w    = bid * 4 + (threadIdx.x >> 6);   // wave id in [0, 8192)
    int lane = threadIdx.x & 63;
    int b  = w >> 9;           // 512 waves per batch
    int r  = w & 511;          // gathered index
    int k  = r >> 8;           // which of the 2 sections
    int wp = r & 255;          // word within section
    int sec = top_idx[b*2 + k];
    int s   = sec * WORDL + wp;
    float cv = coverage[(size_t)b * SRCLEN + s];
    const float4* ef = (const float4*)(enc_feature + ((size_t)b * SRCLEN + s) * DIM);
    const float4* df = (const float4*)(dec_feature + (size_t)b * DIM);
    const float4* vv = (const float4*)v;
    const float4* wc = (const float4*)w_cov;
    float acc = 0.f;
    #pragma unroll
    for (int q = 0; q < 4; q++) {
        int e4 = q * 64 + lane;                  // coalesced: 64 lanes x 16B
        float4 a = ef[e4], d = df[e4], wcv = wc[e4], vt = vv[e4];
        acc += fast_tanh(a.x + d.x + cv * wcv.x) * vt.x;
        acc += fast_tanh(a.y + d.y + cv * wcv.y) * vt.y;
        acc += fast_tanh(a.z + d.z + cv * wcv.z) * vt.z;
        acc += fast_tanh(a.w + d.w + cv * wcv.w) * vt.w;
    }
    #pragma unroll
    for (int off = 32; off; off >>= 1) acc += __shfl_down(acc, off);
    if (lane == 0) score_g[b * GL + r] = acc;
}

// ---------------------------------------------------------------------------
// K3: per-batch masked softmax over 512 gathered scores + focus scaling +
//     global renorm + zero-fill attn row + scatter into attn_dist/cov_out.
// Algebra: attn = f_k*e*mask / sum(f_k*e*mask)  (inner softmax norm cancels)
// grid 16 x 256 threads, 2 elements/thread.
// ---------------------------------------------------------------------------
__device__ __forceinline__ float block_reduce(float val, int is_max) {
    __shared__ float red[4];
    int lane = threadIdx.x & 63, wid = threadIdx.x >> 6;
    #pragma unroll
    for (int off = 32; off; off >>= 1) {
        float o = __shfl_down(val, off);
        val = is_max ? fmaxf(val, o) : val + o;
    }
    if (lane == 0) red[wid] = val;
    __syncthreads();
    if (threadIdx.x == 0) {
        float r = red[0];
        for (int i = 1; i < 4; i++) r = is_max ? fmaxf(r, red[i]) : r + red[i];
        red[0] = r;
    }
    __syncthreads();
    float result = red[0];
    __syncthreads();   // protect red[] before next call
    return result;
}

__global__ __launch_bounds__(256) void k_softmax_scatter(
    const float* __restrict__ enc_mask, const float* __restrict__ coverage,
    const int* __restrict__ top_idx, const float* __restrict__ top_val,
    const float* __restrict__ score_g,
    float* __restrict__ attn_g, float* __restrict__ attn_out,
    float* __restrict__ cov_out)
{
    int b = blockIdx.x;
    int t = threadIdx.x;

    // zero-fill this batch's attn_dist row (4096 floats = 1024 float4)
    float4 z = {0.f, 0.f, 0.f, 0.f};
    float4* arow = (float4*)(attn_out + (size_t)b * SRCLEN);
    #pragma unroll
    for (int u = 0; u < 4; u++) arow[t + u * 256] = z;

    float sc[2], mk[2], fv[2];
    int ss[2];
    #pragma unroll
    for (int u = 0; u < 2; u++) {
        int r  = t + u * 256;
        int k  = r >> 8, wp = r & 255;
        int sec = top_idx[b*2 + k];
        int s   = sec * WORDL + wp;
        ss[u] = s;
        sc[u] = score_g[b * GL + r];
        mk[u] = enc_mask[(size_t)b * SRCLEN + s];
        fv[u] = top_val[b*2 + k];
    }
    float m  = block_reduce(fmaxf(sc[0], sc[1]), 1);   // barriers inside also
    float e0 = __expf(sc[0] - m), e1 = __expf(sc[1] - m);
    float Tn = block_reduce(fv[0]*e0*mk[0] + fv[1]*e1*mk[1], 0);
    float inv = 1.0f / Tn;
    __syncthreads();   // ensure all zero-fills landed before scatter
    #pragma unroll
    for (int u = 0; u < 2; u++) {
        int r = t + u * 256;
        float a = fv[u] * (u ? e1 : e0) * mk[u] * inv;
        attn_g[b * GL + r] = a;
        attn_out[(size_t)b * SRCLEN + ss[u]] = a;
        cov_out [(size_t)b * SRCLEN + ss[u]] = coverage[(size_t)b * SRCLEN + ss[u]] + a;
    }
}

// ---------------------------------------------------------------------------
// K4: context[b][:] = sum over 512 gathered rows of attn * enc_output[row][:]
// grid (16 splits, 16 batches) x 256 threads; each block sums 32 rows,
// float4-coalesced, atomicAdd partials (context zeroed by K1).
// ---------------------------------------------------------------------------
__global__ __launch_bounds__(256) void k_context(
    const float* __restrict__ enc_output, const int* __restrict__ top_idx,
    const float* __restrict__ attn_g, float* __restrict__ context)
{
    int b  = blockIdx.y;
    int sp = blockIdx.x;        // 0..15
    int t  = threadIdx.x;       // float4 index over DIM/4 = 256
    int i0 = top_idx[b*2], i1 = top_idx[b*2 + 1];
    float4 acc = {0.f, 0.f, 0.f, 0.f};
    #pragma unroll 4
    for (int j = 0; j < 32; j++) {
        int r  = sp * 32 + j;
        int k  = r >> 8, wp = r & 255;
        int s  = (k ? i1 : i0) * WORDL + wp;
        float a = attn_g[b * GL + r];
        float4 e = ((const float4*)(enc_output + ((size_t)b * SRCLEN + s) * DIM))[t];
        acc.x += a * e.x; acc.y += a * e.y; acc.z += a * e.z; acc.w += a * e.w;
    }
    float* ctx = context + (size_t)b * DIM + t * 4;
    atomicAdd(ctx + 0, acc.x);
    atomicAdd(ctx + 1, acc.y);
    atomicAdd(ctx + 2, acc.z);
    atomicAdd(ctx + 3, acc.w);
}

// ---------------------------------------------------------------------------
extern "C" void kernel_launch(void* const* d_in, const int* in_sizes, int n_in,
                              void* d_out, int out_size, void* d_ws, size_t ws_size,
                              hipStream_t stream) {
    const float* dec_hidden  = (const float*)d_in[0];   // [16,1024]
    const float* enc_output  = (const float*)d_in[1];   // [16,4096,1024]
    const float* enc_feature = (const float*)d_in[2];   // [16,4096,1024]
    const float* enc_mask    = (const float*)d_in[3];   // [16,4096]
    // d_in[4] = sec_attn : unused by the reference
    const float* coverage    = (const float*)d_in[5];   // [16,4096]
    const float* focus       = (const float*)d_in[6];   // [16,16]
    const float* W_dec       = (const float*)d_in[7];   // [1024,1024]
    const float* b_dec       = (const float*)d_in[8];   // [1024]
    const float* v           = (const float*)d_in[9];   // [1024]
    const float* w_cov       = (const float*)d_in[10];  // [1024]

    float* out      = (float*)d_out;
    float* context  = out;                        // 16*1024  = 16384
    float* attn_out = out + 16384;                // 16*4096  = 65536
    float* cov_out  = out + 16384 + 65536;        // 16*4096  = 65536

    float* ws          = (float*)d_ws;
    float* dec_feature = ws;                      // 16384 floats
    int*   top_idx     = (int*)(ws + 16384);      // 32 ints
    float* top_val     = ws + 16384 + 32;         // 32 floats
    float* score_g     = ws + 16448;              // 16*512 = 8192
    float* attn_g      = ws + 24640;              // 16*512 = 8192

    k_decproj_topk<<<dim3(17, 16), 256, 0, stream>>>(
        dec_hidden, W_dec, b_dec, focus, dec_feature, top_idx, top_val, context);

    k_score_cov<<<dim3(2112), 256, 0, stream>>>(
        enc_feature, coverage, dec_feature, v, w_cov, top_idx, score_g, cov_out);

    k_softmax_scatter<<<dim3(16), 256, 0, stream>>>(
        enc_mask, coverage, top_idx, top_val, score_g, attn_g, attn_out, cov_out);

    k_context<<<dim3(16, 16), 256, 0, stream>>>(
        enc_output, top_idx, attn_g, context);
}